// Round 12
// baseline (44.027 us; speedup 1.0000x reference)
//
#include <hip/hip_runtime.h>

// Contrast-depth loss:
//   d = out - label   (elementwise, [B,32,32] fp32)
//   loss = mean over (b, 8 neighbors, 30x30 centers) of
//          (d[y+dy][x+dx] - d[y][x])^2, centers y,x in [1,30]
//
// R12 design: R8's proven per-thread 6x6-center tile (exact 32x32 tiling),
// but 64-thread (1-wave) blocks: grid 6400 = 25 blocks/CU -> tail imbalance
// ~4% (vs 6.25/CU = ~16% at grid 1600), and block reduction collapses to a
// pure wave shuffle (no LDS, no barrier anywhere). Nontemporal loads (nt)
// for the once-read stream. Two-kernel finish (proven: every fused finisher
// -- threadfence, atomic, memset node -- lost 10-70us).

#define BTHREADS 64

typedef float f2 __attribute__((ext_vector_type(2)));

__global__ __launch_bounds__(BTHREADS) void cdl_partial(
    const float* __restrict__ outp,
    const float* __restrict__ labp,
    float* __restrict__ partial,
    int nimg)
{
    const int t  = threadIdx.x;               // 0..63, one wave
    const int tg = blockIdx.x * BTHREADS + t;
    const int img = tg / 25;                  // 25 tiles per image
    const int tau = tg - img * 25;
    const int ty = tau / 5, tx = tau - ty * 5;

    float a0 = 0.f, a1 = 0.f, a2 = 0.f, a3 = 0.f;

    if (img < nimg) {
        // patch origin: row 6ty, col 6tx (6tx even -> 8B-aligned f2 loads)
        const long long fb = (long long)img * 1024 + (6 * ty) * 32 + 6 * tx;
        const f2* ob = (const f2*)(outp + fb);
        const f2* lb = (const f2*)(labp + fb);

        // ---- 64 independent nontemporal 8B loads, immediate offsets ----
        f2 ov[8][4], lv[8][4];
        #pragma unroll
        for (int r = 0; r < 8; ++r) {
            #pragma unroll
            for (int c = 0; c < 4; ++c) ov[r][c] = __builtin_nontemporal_load(ob + r * 16 + c);
        }
        #pragma unroll
        for (int r = 0; r < 8; ++r) {
            #pragma unroll
            for (int c = 0; c < 4; ++c) lv[r][c] = __builtin_nontemporal_load(lb + r * 16 + c);
        }

        // ---- subtract into 8x8 patch ----
        float d[8][8];
        #pragma unroll
        for (int r = 0; r < 8; ++r) {
            #pragma unroll
            for (int c = 0; c < 4; ++c) {
                d[r][2 * c]     = ov[r][c].x - lv[r][c].x;
                d[r][2 * c + 1] = ov[r][c].y - lv[r][c].y;
            }
        }

        // ---- 6x6 centers, 8 neighbors each; 4 rotating accumulators ----
        #pragma unroll
        for (int cy = 1; cy <= 6; ++cy) {
            #pragma unroll
            for (int cx = 1; cx <= 6; ++cx) {
                const float c = d[cy][cx];
                float s = 0.f, v;
                v = d[cy - 1][cx - 1] - c; s += v * v;
                v = d[cy - 1][cx    ] - c; s += v * v;
                v = d[cy - 1][cx + 1] - c; s += v * v;
                v = d[cy    ][cx - 1] - c; s += v * v;
                v = d[cy    ][cx + 1] - c; s += v * v;
                v = d[cy + 1][cx - 1] - c; s += v * v;
                v = d[cy + 1][cx    ] - c; s += v * v;
                v = d[cy + 1][cx + 1] - c; s += v * v;
                const int k = (cy * 6 + cx) & 3;
                if (k == 0) a0 += s; else if (k == 1) a1 += s;
                else if (k == 2) a2 += s; else a3 += s;
            }
        }
    }

    float acc = (a0 + a1) + (a2 + a3);

    // ---- wave reduction only (64-thread block == 1 wave): no LDS/barrier ----
    #pragma unroll
    for (int off = 32; off; off >>= 1) acc += __shfl_down(acc, off, 64);
    if (t == 0) partial[blockIdx.x] = acc;
}

__global__ __launch_bounds__(256) void cdl_final(
    const float* __restrict__ partial,
    float* __restrict__ out,
    int np,
    float inv_count)
{
    __shared__ float red[4];
    const int t = threadIdx.x;
    float acc = 0.f;
    for (int i = t; i < np; i += 256) acc += partial[i];
    #pragma unroll
    for (int off = 32; off; off >>= 1) acc += __shfl_down(acc, off, 64);
    if ((t & 63) == 0) red[t >> 6] = acc;
    __syncthreads();
    if (t == 0) out[0] = (red[0] + red[1] + red[2] + red[3]) * inv_count;
}

extern "C" void kernel_launch(void* const* d_in, const int* in_sizes, int n_in,
                              void* d_out, int out_size, void* d_ws, size_t ws_size,
                              hipStream_t stream) {
    const float* outp = (const float*)d_in[0];
    const float* labp = (const float*)d_in[1];
    float* partial = (float*)d_ws;
    const int nimg = in_sizes[0] / 1024;                          // B (H=W=32)
    const long long ntask = (long long)nimg * 25;
    const int nblocks = (int)((ntask + BTHREADS - 1) / BTHREADS); // 6400 for B=16384
    const float inv_count = 1.0f / ((float)nimg * 8.0f * 900.0f);

    cdl_partial<<<nblocks, BTHREADS, 0, stream>>>(outp, labp, partial, nimg);
    cdl_final<<<1, 256, 0, stream>>>(partial, (float*)d_out, nblocks, inv_count);
}

// Round 13
// 34.684 us; speedup vs baseline: 1.2694x; 1.2694x over previous
//
#include <hip/hip_runtime.h>

// Contrast-depth loss:
//   d = out - label   (elementwise, [B,32,32] fp32)
//   loss = mean over (b, 8 neighbors, 30x30 centers) of
//          (d[y+dy][x+dx] - d[y][x])^2, centers y,x in [1,30]
//
// R13 design: R8's proven per-thread 6x6-center tile (exact 32x32 tiling)
// with 64-thread (1-wave) blocks: grid 6400 = 25 blocks/CU (tail imbalance
// ~4% vs ~16% at grid 1600) and the block reduction is a pure wave shuffle
// (no LDS, no barriers anywhere). PLAIN loads (R12's nontemporal hints broke
// L3 absorption of the 1.56x tile-overlap re-reads: wall +15us). Two-kernel
// finish (every fused finisher -- threadfence/atomic/memset -- lost 10-70us).

#define BTHREADS 64

__global__ __launch_bounds__(BTHREADS) void cdl_partial(
    const float* __restrict__ outp,
    const float* __restrict__ labp,
    float* __restrict__ partial,
    int nimg)
{
    const int t  = threadIdx.x;               // 0..63, one wave
    const int tg = blockIdx.x * BTHREADS + t;
    const int img = tg / 25;                  // 25 tiles per image
    const int tau = tg - img * 25;
    const int ty = tau / 5, tx = tau - ty * 5;

    float a0 = 0.f, a1 = 0.f, a2 = 0.f, a3 = 0.f;

    if (img < nimg) {
        // patch origin: row 6ty, col 6tx (6tx even -> 8B-aligned float2 loads)
        const long long fb = (long long)img * 1024 + (6 * ty) * 32 + 6 * tx;
        const float2* ob = (const float2*)(outp + fb);
        const float2* lb = (const float2*)(labp + fb);

        // ---- 64 independent 8B loads, immediate offsets off two bases ----
        float2 ov[8][4], lv[8][4];
        #pragma unroll
        for (int r = 0; r < 8; ++r) {
            #pragma unroll
            for (int c = 0; c < 4; ++c) ov[r][c] = ob[r * 16 + c];
        }
        #pragma unroll
        for (int r = 0; r < 8; ++r) {
            #pragma unroll
            for (int c = 0; c < 4; ++c) lv[r][c] = lb[r * 16 + c];
        }

        // ---- subtract into 8x8 patch ----
        float d[8][8];
        #pragma unroll
        for (int r = 0; r < 8; ++r) {
            #pragma unroll
            for (int c = 0; c < 4; ++c) {
                d[r][2 * c]     = ov[r][c].x - lv[r][c].x;
                d[r][2 * c + 1] = ov[r][c].y - lv[r][c].y;
            }
        }

        // ---- 6x6 centers, 8 neighbors each; 4 rotating accumulators ----
        #pragma unroll
        for (int cy = 1; cy <= 6; ++cy) {
            #pragma unroll
            for (int cx = 1; cx <= 6; ++cx) {
                const float c = d[cy][cx];
                float s = 0.f, v;
                v = d[cy - 1][cx - 1] - c; s += v * v;
                v = d[cy - 1][cx    ] - c; s += v * v;
                v = d[cy - 1][cx + 1] - c; s += v * v;
                v = d[cy    ][cx - 1] - c; s += v * v;
                v = d[cy    ][cx + 1] - c; s += v * v;
                v = d[cy + 1][cx - 1] - c; s += v * v;
                v = d[cy + 1][cx    ] - c; s += v * v;
                v = d[cy + 1][cx + 1] - c; s += v * v;
                const int k = (cy * 6 + cx) & 3;
                if (k == 0) a0 += s; else if (k == 1) a1 += s;
                else if (k == 2) a2 += s; else a3 += s;
            }
        }
    }

    float acc = (a0 + a1) + (a2 + a3);

    // ---- wave reduction only (64-thread block == 1 wave): no LDS/barrier ----
    #pragma unroll
    for (int off = 32; off; off >>= 1) acc += __shfl_down(acc, off, 64);
    if (t == 0) partial[blockIdx.x] = acc;
}

__global__ __launch_bounds__(256) void cdl_final(
    const float* __restrict__ partial,
    float* __restrict__ out,
    int np,
    float inv_count)
{
    __shared__ float red[4];
    const int t = threadIdx.x;
    float acc = 0.f;
    for (int i = t; i < np; i += 256) acc += partial[i];
    #pragma unroll
    for (int off = 32; off; off >>= 1) acc += __shfl_down(acc, off, 64);
    if ((t & 63) == 0) red[t >> 6] = acc;
    __syncthreads();
    if (t == 0) out[0] = (red[0] + red[1] + red[2] + red[3]) * inv_count;
}

extern "C" void kernel_launch(void* const* d_in, const int* in_sizes, int n_in,
                              void* d_out, int out_size, void* d_ws, size_t ws_size,
                              hipStream_t stream) {
    const float* outp = (const float*)d_in[0];
    const float* labp = (const float*)d_in[1];
    float* partial = (float*)d_ws;
    const int nimg = in_sizes[0] / 1024;                          // B (H=W=32)
    const long long ntask = (long long)nimg * 25;
    const int nblocks = (int)((ntask + BTHREADS - 1) / BTHREADS); // 6400 for B=16384
    const float inv_count = 1.0f / ((float)nimg * 8.0f * 900.0f);

    cdl_partial<<<nblocks, BTHREADS, 0, stream>>>(outp, labp, partial, nimg);
    cdl_final<<<1, 256, 0, stream>>>(partial, (float*)d_out, nblocks, inv_count);
}